// Round 5
// baseline (57.674 us; speedup 1.0000x reference)
//
#include <hip/hip_runtime.h>

#define NCLS 1024
#define EPS_C 1e-5f
#define LOSS_BLOCKS 2048   // 2048 blocks * 4 waves * 8 rows/wave = 65536 rows
#define HW_WAVES 16        // waves in the histogram block

// ---------------- Kernel 1: fused histogram + min + weights (single block) ----------------
// Per-wave private LDS histograms kill cross-wave same-address atomic serialization.
__global__ __launch_bounds__(1024) void hist_weights_kernel(const int* __restrict__ tgt,
                                                            float* __restrict__ w,
                                                            int B) {
    __shared__ unsigned int h[HW_WAVES][NCLS];
    __shared__ float smin[16];
    const int tid = threadIdx.x;
    const int wv  = tid >> 6;

    #pragma unroll
    for (int i = 0; i < HW_WAVES; ++i) h[i][tid] = 0u;
    __syncthreads();

    const int4* t4 = (const int4*)tgt;
    const int n4 = B >> 2;
    for (int i = tid; i < n4; i += 1024) {
        int4 v = t4[i];
        atomicAdd(&h[wv][v.x & (NCLS - 1)], 1u);
        atomicAdd(&h[wv][v.y & (NCLS - 1)], 1u);
        atomicAdd(&h[wv][v.z & (NCLS - 1)], 1u);
        atomicAdd(&h[wv][v.w & (NCLS - 1)], 1u);
    }
    __syncthreads();

    unsigned int cu = 0;
    #pragma unroll
    for (int i = 0; i < HW_WAVES; ++i) cu += h[i][tid];
    const float c = (float)cu;

    float m = c;
    #pragma unroll
    for (int off = 32; off > 0; off >>= 1) m = fminf(m, __shfl_xor(m, off));
    if ((tid & 63) == 0) smin[tid >> 6] = m;
    __syncthreads();
    if (tid == 0) {
        float mm = smin[0];
        #pragma unroll
        for (int i = 1; i < 16; ++i) mm = fminf(mm, smin[i]);
        smin[0] = mm;
    }
    __syncthreads();
    w[tid] = smin[0] / c + EPS_C;
}

// ---------------- helpers ----------------
__device__ __forceinline__ float sumexp16(float4 a, float4 b, float4 c, float4 d) {
    return __expf(a.x) + __expf(a.y) + __expf(a.z) + __expf(a.w)
         + __expf(b.x) + __expf(b.y) + __expf(b.z) + __expf(b.w)
         + __expf(c.x) + __expf(c.y) + __expf(c.z) + __expf(c.w)
         + __expf(d.x) + __expf(d.y) + __expf(d.z) + __expf(d.w);
}

// Extract element t (0..1023) of the row spread across the wave's 4 float4 regs.
// Lane L holds elements {256*r + 4*L + c}. t is wave-uniform -> scalar selects + 1 shfl.
__device__ __forceinline__ float extract_elem(float4 v0, float4 v1, float4 v2, float4 v3, int t) {
    const int reg  = (t >> 8) & 3;
    const int comp = t & 3;
    float4 vr = (reg == 0) ? v0 : (reg == 1) ? v1 : (reg == 2) ? v2 : v3;
    float  x  = (comp == 0) ? vr.x : (comp == 1) ? vr.y : (comp == 2) ? vr.z : vr.w;
    return __shfl(x, (t >> 2) & 63);
}

// ---------------- Kernel 2: per-row sum-exp + focal loss -> per-block partials ----------------
// 8 rows/wave; xt extracted in-register during the streaming loop (no end-of-wave gather).
__global__ __launch_bounds__(256) void loss_kernel(const float* __restrict__ inp,
                                                   const int* __restrict__ tgt,
                                                   const float* __restrict__ w,
                                                   float* __restrict__ partials,
                                                   int B) {
    const int wave  = threadIdx.x >> 6;
    const int lane  = threadIdx.x & 63;
    const int gwave = blockIdx.x * 4 + wave;
    const int base  = gwave * 8;

    float acc = 0.0f;

    if (base + 8 <= B) {
        float s[8];
        float myXt = 0.0f;
        int   myT  = 0;
        const float4* rp = (const float4*)(inp + (size_t)base * NCLS);
        #pragma unroll
        for (int rr = 0; rr < 8; ++rr) {
            float4 a0 = rp[lane];
            float4 a1 = rp[lane + 64];
            float4 a2 = rp[lane + 128];
            float4 a3 = rp[lane + 192];
            const int t = tgt[base + rr] & (NCLS - 1);   // wave-uniform scalar load
            const float x = extract_elem(a0, a1, a2, a3, t);
            if (lane == rr) { myXt = x; myT = t; }
            s[rr] = sumexp16(a0, a1, a2, a3);
            rp += NCLS / 4;
        }
        // one butterfly, 8 independent chains
        #pragma unroll
        for (int off = 32; off > 0; off >>= 1) {
            #pragma unroll
            for (int rr = 0; rr < 8; ++rr) s[rr] += __shfl_xor(s[rr], off);
        }
        // lane r (r<8) takes row base+r
        float myS = s[0];
        #pragma unroll
        for (int rr = 1; rr < 8; ++rr) myS = (lane == rr) ? s[rr] : myS;

        float l = 0.0f;
        if (lane < 8) {
            const float lp = myXt - __logf(myS);
            const float p  = __expf(lp);
            const float o  = 1.0f - p;
            l = -o * o * lp * w[myT];       // 4KB w: L2-hot gather
        }
        l += __shfl_xor(l, 1);
        l += __shfl_xor(l, 2);
        l += __shfl_xor(l, 4);
        acc = l;
    } else {
        // generic tail (dead at B=65536)
        for (int r = base; r < B && r < base + 8; ++r) {
            const float4* rp = (const float4*)(inp + (size_t)r * NCLS);
            float4 a0 = rp[lane], a1 = rp[lane + 64], a2 = rp[lane + 128], a3 = rp[lane + 192];
            const int t = tgt[r] & (NCLS - 1);
            const float x = extract_elem(a0, a1, a2, a3, t);
            float s0 = sumexp16(a0, a1, a2, a3);
            #pragma unroll
            for (int off = 32; off > 0; off >>= 1) s0 += __shfl_xor(s0, off);
            const float lp = x - __logf(s0);
            const float p  = __expf(lp);
            const float o  = 1.0f - p;
            if (lane == 0) acc += -o * o * lp * w[t];
        }
    }

    __shared__ float sm[4];
    if (lane == 0) sm[wave] = acc;
    __syncthreads();
    if (threadIdx.x == 0)
        partials[blockIdx.x] = sm[0] + sm[1] + sm[2] + sm[3];
}

// ---------------- Kernel 3: reduce partials + finalize (launch-overhead-bound) ----------------
__global__ __launch_bounds__(256) void reduce_finalize(const float* __restrict__ partials,
                                                       float* __restrict__ out,
                                                       int n, float invB) {
    __shared__ float sm[4];
    float s = 0.0f;
    for (int i = threadIdx.x; i < n; i += 256) s += partials[i];
    #pragma unroll
    for (int off = 32; off > 0; off >>= 1) s += __shfl_xor(s, off);
    if ((threadIdx.x & 63) == 0) sm[threadIdx.x >> 6] = s;
    __syncthreads();
    if (threadIdx.x == 0)
        out[0] = (sm[0] + sm[1] + sm[2] + sm[3]) * invB;
}

extern "C" void kernel_launch(void* const* d_in, const int* in_sizes, int n_in,
                              void* d_out, int out_size, void* d_ws, size_t ws_size,
                              hipStream_t stream) {
    const float* inp = (const float*)d_in[0];
    const int*   tgt = (const int*)d_in[1];
    const int B = in_sizes[1];          // 65536

    float* w        = (float*)d_ws;                       // 1024 floats
    float* partials = (float*)((char*)d_ws + 4096);       // LOSS_BLOCKS floats

    hist_weights_kernel<<<1, 1024, 0, stream>>>(tgt, w, B);
    loss_kernel<<<LOSS_BLOCKS, 256, 0, stream>>>(inp, tgt, w, partials, B);
    reduce_finalize<<<1, 256, 0, stream>>>(partials, (float*)d_out,
                                           LOSS_BLOCKS, 1.0f / (float)B);
}

// Round 6
// 53.358 us; speedup vs baseline: 1.0809x; 1.0809x over previous
//
#include <hip/hip_runtime.h>

#define NCLS 1024
#define EPS_C 1e-5f
#define LOSS_BLOCKS 2048   // 2048 blocks * 4 waves * 8 rows/wave = 65536 rows
#define HIST_BLOCKS 16

// ---------------- Kernel A: partial histograms (16 blocks, no atom.global, no memset) ----------------
__global__ __launch_bounds__(1024) void hist_parts_kernel(const int* __restrict__ tgt,
                                                          unsigned int* __restrict__ parts,
                                                          int B) {
    __shared__ unsigned int h[16][NCLS];   // per-wave private hists, 64 KB
    const int tid = threadIdx.x;
    const int wv  = tid >> 6;
    #pragma unroll
    for (int i = 0; i < 16; ++i) h[i][tid] = 0u;
    __syncthreads();

    const int4* t4 = (const int4*)tgt;
    const int n4 = B >> 2;
    for (int i = blockIdx.x * 1024 + tid; i < n4; i += HIST_BLOCKS * 1024) {
        int4 v = t4[i];
        atomicAdd(&h[wv][v.x & (NCLS - 1)], 1u);
        atomicAdd(&h[wv][v.y & (NCLS - 1)], 1u);
        atomicAdd(&h[wv][v.z & (NCLS - 1)], 1u);
        atomicAdd(&h[wv][v.w & (NCLS - 1)], 1u);
    }
    __syncthreads();

    unsigned int cu = 0;
    #pragma unroll
    for (int i = 0; i < 16; ++i) cu += h[i][tid];
    parts[blockIdx.x * NCLS + tid] = cu;
}

// ---------------- Kernel B: merge partials -> weights ----------------
__global__ __launch_bounds__(1024) void weights_kernel(const unsigned int* __restrict__ parts,
                                                       float* __restrict__ w) {
    __shared__ float smin[16];
    const int tid = threadIdx.x;
    unsigned int cu = 0;
    #pragma unroll
    for (int k = 0; k < HIST_BLOCKS; ++k) cu += parts[k * NCLS + tid];
    const float c = (float)cu;

    float m = c;
    #pragma unroll
    for (int off = 32; off > 0; off >>= 1) m = fminf(m, __shfl_xor(m, off));
    if ((tid & 63) == 0) smin[tid >> 6] = m;
    __syncthreads();
    if (tid == 0) {
        float mm = smin[0];
        #pragma unroll
        for (int i = 1; i < 16; ++i) mm = fminf(mm, smin[i]);
        smin[0] = mm;
    }
    __syncthreads();
    w[tid] = smin[0] / c + EPS_C;
}

// ---------------- helpers ----------------
__device__ __forceinline__ float sumexp16(float4 a, float4 b, float4 c, float4 d) {
    return __expf(a.x) + __expf(a.y) + __expf(a.z) + __expf(a.w)
         + __expf(b.x) + __expf(b.y) + __expf(b.z) + __expf(b.w)
         + __expf(c.x) + __expf(c.y) + __expf(c.z) + __expf(c.w)
         + __expf(d.x) + __expf(d.y) + __expf(d.z) + __expf(d.w);
}

// ---------------- Kernel C: per-row sum-exp + focal loss -> per-block partials ----------------
// EXACT round-3 hot loop (best measured: loss ~46.5us). Do not touch.
__global__ __launch_bounds__(256) void loss_kernel(const float* __restrict__ inp,
                                                   const int* __restrict__ tgt,
                                                   const float* __restrict__ w,
                                                   float* __restrict__ partials,
                                                   int B) {
    const int wave  = threadIdx.x >> 6;
    const int lane  = threadIdx.x & 63;
    const int gwave = blockIdx.x * 4 + wave;
    const int base  = gwave * 8;

    float acc = 0.0f;

    if (base + 8 <= B) {
        float s[8];
        const float4* rp = (const float4*)(inp + (size_t)base * NCLS);
        #pragma unroll
        for (int rr = 0; rr < 8; ++rr) {
            float4 a0 = rp[lane];
            float4 a1 = rp[lane + 64];
            float4 a2 = rp[lane + 128];
            float4 a3 = rp[lane + 192];
            s[rr] = sumexp16(a0, a1, a2, a3);
            rp += NCLS / 4;
        }
        // one butterfly, 8 independent chains
        #pragma unroll
        for (int off = 32; off > 0; off >>= 1) {
            #pragma unroll
            for (int rr = 0; rr < 8; ++rr) s[rr] += __shfl_xor(s[rr], off);
        }
        // lane r (r<8) takes row base+r
        float myS = s[0];
        #pragma unroll
        for (int rr = 1; rr < 8; ++rr) myS = (lane == rr) ? s[rr] : myS;

        float l = 0.0f;
        if (lane < 8) {
            const int row = base + lane;
            const int t = tgt[row] & (NCLS - 1);
            const float xt = inp[(size_t)row * NCLS + t];   // L2/L3-hot gather
            const float lp = xt - __logf(myS);
            const float p  = __expf(lp);
            const float o  = 1.0f - p;
            l = -o * o * lp * w[t];
        }
        l += __shfl_xor(l, 1);
        l += __shfl_xor(l, 2);
        l += __shfl_xor(l, 4);
        acc = l;
    } else {
        // generic tail (dead at B=65536)
        for (int r = base; r < B && r < base + 8; ++r) {
            const float4* rp = (const float4*)(inp + (size_t)r * NCLS);
            float4 a0 = rp[lane], a1 = rp[lane + 64], a2 = rp[lane + 128], a3 = rp[lane + 192];
            float s0 = sumexp16(a0, a1, a2, a3);
            #pragma unroll
            for (int off = 32; off > 0; off >>= 1) s0 += __shfl_xor(s0, off);
            const int t = tgt[r] & (NCLS - 1);
            const float xt = inp[(size_t)r * NCLS + t];
            const float lp = xt - __logf(s0);
            const float p  = __expf(lp);
            const float o  = 1.0f - p;
            if (lane == 0) acc += -o * o * lp * w[t];
        }
    }

    __shared__ float sm[4];
    if (lane == 0) sm[wave] = acc;
    __syncthreads();
    if (threadIdx.x == 0)
        partials[blockIdx.x] = sm[0] + sm[1] + sm[2] + sm[3];
}

// ---------------- Kernel D: reduce partials + finalize ----------------
__global__ __launch_bounds__(1024) void reduce_finalize(const float* __restrict__ partials,
                                                        float* __restrict__ out,
                                                        int n, float invB) {
    __shared__ float sm[16];
    float s = 0.0f;
    for (int i = threadIdx.x; i < n; i += 1024) s += partials[i];
    #pragma unroll
    for (int off = 32; off > 0; off >>= 1) s += __shfl_xor(s, off);
    if ((threadIdx.x & 63) == 0) sm[threadIdx.x >> 6] = s;
    __syncthreads();
    if (threadIdx.x == 0) {
        float t = 0.0f;
        #pragma unroll
        for (int i = 0; i < 16; ++i) t += sm[i];
        out[0] = t * invB;
    }
}

extern "C" void kernel_launch(void* const* d_in, const int* in_sizes, int n_in,
                              void* d_out, int out_size, void* d_ws, size_t ws_size,
                              hipStream_t stream) {
    const float* inp = (const float*)d_in[0];
    const int*   tgt = (const int*)d_in[1];
    const int B = in_sizes[1];          // 65536

    float*        w        = (float*)d_ws;                          // 1024 f32
    float*        partials = (float*)((char*)d_ws + 4096);          // LOSS_BLOCKS f32
    unsigned int* parts    = (unsigned int*)((char*)d_ws + 16384);  // 16 x 1024 u32

    hist_parts_kernel<<<HIST_BLOCKS, 1024, 0, stream>>>(tgt, parts, B);
    weights_kernel<<<1, 1024, 0, stream>>>(parts, w);
    loss_kernel<<<LOSS_BLOCKS, 256, 0, stream>>>(inp, tgt, w, partials, B);
    reduce_finalize<<<1, 1024, 0, stream>>>(partials, (float*)d_out,
                                            LOSS_BLOCKS, 1.0f / (float)B);
}